// Round 18
// baseline (192.340 us; speedup 1.0000x reference)
//
#include <hip/hip_runtime.h>
#include <math.h>

// Problem geometry (round-14 emit geometry, fused single-pass)
#define T_LEN   160000
#define NROW    128        // 64 rows of x then 64 rows of n
#define CH      32         // samples per chunk
#define NCH     5000       // CH*NCH == T_LEN
#define OWN_W   62         // own chunks per wave (+2 warm = 64 staged)
#define B_OWN   (4 * OWN_W)      // 248 own chunks per block
#define TILES   21               // ceil(5000/248)
#define NBLK    (NROW * TILES)   // 2688
#define ROW4    40000            // float4 per row
#define NSTATE  (NBLK + 1)       // state flags + ticket

// HP biquad: y = x - 2 x1 + x2 + 1.99599 y1 - 0.996 y2
#define C1_HP ( 1.99599)
#define C2_HP (-0.996)
#define C1F   ( 1.99599f)
#define C2F   (-0.996f)

#define GLOBAL_AS __attribute__((address_space(1)))
#define SHARED_AS __attribute__((address_space(3)))

// involutive swizzle (bits 3,4,5 XOR into 0,1,2) — async-load compatible
__device__ __forceinline__ int swzf(int F) { return F ^ ((F >> 3) & 7); }
__device__ __forceinline__ float clip1f(float v) { return fminf(fmaxf(v, -1.0f), 1.0f); }

// ---------------------------------------------------------------------------
// init: zero the NBLK publish flags + the ticket counter (fresh each launch).
// ---------------------------------------------------------------------------
__global__ void init_kernel(unsigned* __restrict__ st) {
  int i = blockIdx.x * blockDim.x + threadIdx.x;
  if (i < NSTATE) st[i] = 0u;
}

// ---------------------------------------------------------------------------
// fused: single pass. Per block (ticket-assigned tile (row, t)):
//  1. stage 64-chunk wave tiles (async global_load_lds interior / manual edge)
//  2. per-lane local stage-1 end state (f64, zero y-init, true x-history)
//  3. wave affine Kogge-Stone (f64) -> exclusive prefixes + wave maps
//  4. publish block partial (release); wave-0 parallel lookback over row
//     predecessors (acquire+spin) -> exact incoming state S_in
//  5. per-lane exact stage-1 seed; warm lanes via M^-1 backward steps
//  6. round-14 emit: FIR + fused AB (stage1+stage2 zero-z) + e2 shfl +
//     M2 correction + clip + LDS write-back + coalesced store
// ---------------------------------------------------------------------------
__global__ __launch_bounds__(256, 4) void fused_kernel(
    const float* __restrict__ x, const float* __restrict__ nn,
    const float* __restrict__ cx, const float* __restrict__ cn,
    double* __restrict__ pay, unsigned* __restrict__ st,
    unsigned* __restrict__ ticket, float* __restrict__ out) {
  __shared__ float4 ws4[2048];     // 4 waves x 512 float4 = 32 KB
  __shared__ double wmS[4][6];     // per-wave inclusive maps
  __shared__ double SinS[2];       // incoming state for this block
  __shared__ unsigned vidS;

  const int tid = threadIdx.x, lane = tid & 63, wv = tid >> 6;
  if (tid == 0) vidS = atomicAdd(ticket, 1u);
  __syncthreads();
  const unsigned vid = vidS;
  const int row = vid / TILES, tile = vid % TILES;

  const float* src = (row < 64) ? x + (size_t)row * T_LEN
                                : nn + (size_t)(row - 64) * T_LEN;
  const float4* src4 = reinterpret_cast<const float4*>(src);
  const float* cf = (row < 64) ? cx : cn;
  const float A1c = cf[0], A2c = cf[1], B1c = cf[2], B2c = cf[3];

  const int wave_c0 = tile * B_OWN + wv * OWN_W;
  const int cb = wave_c0 - 2 + lane;
  const bool valid = (cb >= 0) && (cb < NCH);
  const int WOFF = wv * 512;
  const long base4 = (long)(wave_c0 - 2) * 8;
  const bool interior = (base4 >= 0) && (base4 + 512 <= (long)ROW4);

  // early lane-0 x-history load
  float2 tp = make_float2(0.f, 0.f);
  if (lane == 0 && valid && cb > 0)
    tp = *reinterpret_cast<const float2*>(src + (long)cb * CH - 2);

  // ---- stage wave tile ----
  if (interior) {
    const int lane_sz = lane ^ ((lane >> 3) & 7);
#pragma unroll
    for (int q = 0; q < 8; ++q)
      __builtin_amdgcn_global_load_lds(
          (const GLOBAL_AS void*)(src4 + base4 + q * 64 + lane_sz),
          (SHARED_AS void*)(ws4 + WOFF + q * 64), 16, 0, 0);
    asm volatile("s_waitcnt vmcnt(0)" ::: "memory");
  } else {
#pragma unroll
    for (int q = 0; q < 8; ++q) {
      int f = q * 64 + lane;
      long g4 = base4 + f;
      float4 v = make_float4(0.f, 0.f, 0.f, 0.f);
      if (g4 >= 0 && g4 < ROW4) v = src4[g4];
      ws4[WOFF + swzf(f)] = v;
    }
  }

  float4 a[8];
#pragma unroll
  for (int q = 0; q < 8; ++q) a[q] = ws4[WOFF + swzf(lane * 8 + q)];

  // x-history (prev chunk tail via shfl; lane0 global)
  float tx = __shfl_up(a[7].w, 1), ty = __shfl_up(a[7].z, 1);
  float x1i, x2i;
  if (valid && cb > 0) {
    if (lane == 0) { x1i = tp.y; x2i = tp.x; }
    else { x1i = tx; x2i = ty; }
  } else { x1i = 0.f; x2i = 0.f; }

  // ---- local stage-1 end state (f64 y, zero-init) ----
  double ey1 = 0.0, ey2 = 0.0;
  {
    float xx1 = x1i, xx2 = x2i;
#pragma unroll
    for (int q = 0; q < 8; ++q) {
#define E1S(XF) { float xt = (XF); \
      float fir = (xt - 2.f * xx1 + xx2); \
      double yv = fma(C1_HP, ey1, fma(C2_HP, ey2, (double)fir)); \
      xx2 = xx1; xx1 = xt; ey2 = ey1; ey1 = yv; }
      E1S(a[q].x) E1S(a[q].y) E1S(a[q].z) E1S(a[q].w)
#undef E1S
    }
  }

  // ---- FIR precompute (input-only; a[] -> fir) ----
  {
    float xp1 = x1i, xp2 = x2i;
#pragma unroll
    for (int q = 0; q < 8; ++q) {
      float4 t = a[q];
      float4 f;
      f.x = t.x - 2.f * xp1 + xp2;
      f.y = t.y - 2.f * t.x + xp1;
      f.z = t.z - 2.f * t.y + t.x;
      f.w = t.w - 2.f * t.z + t.y;
      xp2 = t.z; xp1 = t.w;
      a[q] = f;
    }
  }

  // ---- M = A_hp^CH (f64) ----
  double pm2 = 0.0, pm1 = 0.0, p0 = 1.0;
#pragma unroll
  for (int k = 1; k <= CH; ++k) {
    double pn = C1_HP * p0 + C2_HP * pm1;
    pm2 = pm1; pm1 = p0; p0 = pn;
  }
  const double m00 = p0,  m01 = C2_HP * pm1;
  const double m10 = pm1, m11 = C2_HP * pm2;

  // ---- wave affine KS over own chunks (warm/invalid lanes = identity) ----
  const bool inscan = (lane >= 2) && valid;
  double P00 = inscan ? m00 : 1.0, P01 = inscan ? m01 : 0.0;
  double P10 = inscan ? m10 : 0.0, P11 = inscan ? m11 : 1.0;
  double V1 = inscan ? ey1 : 0.0,  V2 = inscan ? ey2 : 0.0;
#pragma unroll
  for (int off = 1; off < 64; off <<= 1) {
    double u00 = __shfl_up(P00, off), u01 = __shfl_up(P01, off);
    double u10 = __shfl_up(P10, off), u11 = __shfl_up(P11, off);
    double uv1 = __shfl_up(V1, off),  uv2 = __shfl_up(V2, off);
    if (lane >= off) {
      double nv1 = P00 * uv1 + P01 * uv2 + V1;
      double nv2 = P10 * uv1 + P11 * uv2 + V2;
      double n00 = P00 * u00 + P01 * u10, n01 = P00 * u01 + P01 * u11;
      double n10 = P10 * u00 + P11 * u10, n11 = P10 * u01 + P11 * u11;
      P00 = n00; P01 = n01; P10 = n10; P11 = n11; V1 = nv1; V2 = nv2;
    }
  }
  if (lane == 63) {
    wmS[wv][0] = P00; wmS[wv][1] = P01; wmS[wv][2] = P10; wmS[wv][3] = P11;
    wmS[wv][4] = V1;  wmS[wv][5] = V2;
  }
  // exclusive prefix
  double E00 = __shfl_up(P00, 1), E01 = __shfl_up(P01, 1);
  double E10 = __shfl_up(P10, 1), E11 = __shfl_up(P11, 1);
  double EV1 = __shfl_up(V1, 1),  EV2 = __shfl_up(V2, 1);
  if (lane == 0) { E00 = 1.0; E01 = 0.0; E10 = 0.0; E11 = 1.0; EV1 = 0.0; EV2 = 0.0; }
  __syncthreads();

  // ---- publish block partial, then lookback (wave 0) ----
  if (tid == 0) {
    double bP00 = 1.0, bP01 = 0.0, bP10 = 0.0, bP11 = 1.0, bV1 = 0.0, bV2 = 0.0;
#pragma unroll
    for (int w = 0; w < 4; ++w) {
      double w00 = wmS[w][0], w01 = wmS[w][1], w10 = wmS[w][2], w11 = wmS[w][3];
      double wv1 = wmS[w][4], wv2 = wmS[w][5];
      double n00 = w00 * bP00 + w01 * bP10, n01 = w00 * bP01 + w01 * bP11;
      double n10 = w10 * bP00 + w11 * bP10, n11 = w10 * bP01 + w11 * bP11;
      double nv1 = w00 * bV1 + w01 * bV2 + wv1;
      double nv2 = w10 * bV1 + w11 * bV2 + wv2;
      bP00 = n00; bP01 = n01; bP10 = n10; bP11 = n11; bV1 = nv1; bV2 = nv2;
    }
    double* r = pay + (size_t)vid * 6;
    __hip_atomic_store(r + 0, bP00, __ATOMIC_RELAXED, __HIP_MEMORY_SCOPE_AGENT);
    __hip_atomic_store(r + 1, bP01, __ATOMIC_RELAXED, __HIP_MEMORY_SCOPE_AGENT);
    __hip_atomic_store(r + 2, bP10, __ATOMIC_RELAXED, __HIP_MEMORY_SCOPE_AGENT);
    __hip_atomic_store(r + 3, bP11, __ATOMIC_RELAXED, __HIP_MEMORY_SCOPE_AGENT);
    __hip_atomic_store(r + 4, bV1,  __ATOMIC_RELAXED, __HIP_MEMORY_SCOPE_AGENT);
    __hip_atomic_store(r + 5, bV2,  __ATOMIC_RELAXED, __HIP_MEMORY_SCOPE_AGENT);
    __hip_atomic_store(&st[vid], 1u, __ATOMIC_RELEASE, __HIP_MEMORY_SCOPE_AGENT);
  }
  if (wv == 0) {
    double LP00 = 1.0, LP01 = 0.0, LP10 = 0.0, LP11 = 1.0, LV1 = 0.0, LV2 = 0.0;
    if (lane < tile) {
      unsigned idx = (unsigned)row * TILES + lane;
      int guard = 0;
      while (__hip_atomic_load(&st[idx], __ATOMIC_ACQUIRE,
                               __HIP_MEMORY_SCOPE_AGENT) == 0u &&
             ++guard < (1 << 25))
        __builtin_amdgcn_s_sleep(2);
      const double* r = pay + (size_t)idx * 6;
      LP00 = __hip_atomic_load(r + 0, __ATOMIC_RELAXED, __HIP_MEMORY_SCOPE_AGENT);
      LP01 = __hip_atomic_load(r + 1, __ATOMIC_RELAXED, __HIP_MEMORY_SCOPE_AGENT);
      LP10 = __hip_atomic_load(r + 2, __ATOMIC_RELAXED, __HIP_MEMORY_SCOPE_AGENT);
      LP11 = __hip_atomic_load(r + 3, __ATOMIC_RELAXED, __HIP_MEMORY_SCOPE_AGENT);
      LV1  = __hip_atomic_load(r + 4, __ATOMIC_RELAXED, __HIP_MEMORY_SCOPE_AGENT);
      LV2  = __hip_atomic_load(r + 5, __ATOMIC_RELAXED, __HIP_MEMORY_SCOPE_AGENT);
    }
    double S1 = 0.0, S2 = 0.0;
    for (int j = 0; j < tile; ++j) {
      double p00 = __shfl(LP00, j), p01 = __shfl(LP01, j);
      double p10 = __shfl(LP10, j), p11 = __shfl(LP11, j);
      double q1  = __shfl(LV1, j),  q2  = __shfl(LV2, j);
      double n1 = p00 * S1 + p01 * S2 + q1;
      double n2 = p10 * S1 + p11 * S2 + q2;
      S1 = n1; S2 = n2;
    }
    if (lane == 0) { SinS[0] = S1; SinS[1] = S2; }
  }
  __syncthreads();

  // ---- per-lane exact seed ----
  double S1 = SinS[0], S2 = SinS[1];
  for (int w = 0; w < wv; ++w) {
    double n1 = wmS[w][0] * S1 + wmS[w][1] * S2 + wmS[w][4];
    double n2 = wmS[w][2] * S1 + wmS[w][3] * S2 + wmS[w][5];
    S1 = n1; S2 = n2;
  }
  double sd1 = E00 * S1 + E01 * S2 + EV1;
  double sd2 = E10 * S1 + E11 * S2 + EV2;
  // warm lanes: backward via M^-1 (det = 0.996^32)
  {
    double det = 1.0;
#pragma unroll
    for (int k = 0; k < CH; ++k) det *= (-C2_HP);
    double i00 = m11 / det, i01 = -m01 / det, i10 = -m10 / det, i11 = m00 / det;
    double e1o = __shfl(ey1, 1), e2o = __shfl(ey2, 1);
    if (lane == 1) {
      sd1 = i00 * (S1 - ey1) + i01 * (S2 - ey2);
      sd2 = i10 * (S1 - ey1) + i11 * (S2 - ey2);
    } else if (lane == 0) {
      double t1 = i00 * (S1 - e1o) + i01 * (S2 - e2o);
      double t2 = i10 * (S1 - e1o) + i11 * (S2 - e2o);
      sd1 = i00 * (t1 - ey1) + i01 * (t2 - ey2);
      sd2 = i10 * (t1 - ey1) + i11 * (t2 - ey2);
    }
  }
  float y1, y2, v1, v2;
  if (valid && cb > 0) {
    y1 = (float)sd1; y2 = (float)sd2;
    v1 = clip1f(y1); v2 = clip1f(y2);
  } else { y1 = 0.f; y2 = 0.f; v1 = 0.f; v2 = 0.f; }

  // ---- fused AB (stage1 + stage2 zero-z): a[q] := zb ----
  float z1 = 0.f, z2 = 0.f;
  if (valid) {
#define AB(REF) { \
    float yy = fmaf(C1F, y1, fmaf(C2F, y2, (REF))); \
    float vv = clip1f(yy); \
    float zz = fmaf(-A1c, z1, fmaf(-A2c, z2, fmaf(B2c, v2, fmaf(B1c, v1, vv)))); \
    y2 = y1; y1 = yy; v2 = v1; v1 = vv; z2 = z1; z1 = zz; REF = zz; }
#pragma unroll
    for (int q = 0; q < 8; ++q) { AB(a[q].x) AB(a[q].y) AB(a[q].z) AB(a[q].w) }
#undef AB
  }

  // e2 of the two previous chunks via shuffles
  float u1x = __shfl_up(z1, 1), u1y = __shfl_up(z2, 1);
  float u2x = __shfl_up(z1, 2), u2y = __shfl_up(z2, 2);

  // ---- correction + clip, write back to LDS (own lanes only) ----
  if (lane >= 2 && valid) {
    // M2 = A2stage^CH (f32)
    float q2m = 0.f, q1m = 0.f, q0m = 1.f;
#pragma unroll
    for (int k = 0; k < CH; ++k) {
      float qn = -A1c * q0m - A2c * q1m;
      q2m = q1m; q1m = q0m; q0m = qn;
    }
    const float M00 = q0m, M01 = -A2c * q1m, M10 = q1m, M11 = -A2c * q2m;
    float s2x, s2y;
    if (cb == 0)      { s2x = 0.f; s2y = 0.f; }
    else if (cb == 1) { s2x = u1x; s2y = u1y; }
    else {
      s2x = fmaf(M00, u2x, fmaf(M01, u2y, u1x));
      s2y = fmaf(M10, u2x, fmaf(M11, u2y, u1y));
    }
    float h1 = s2x, h2 = s2y;
#define CS(ZB, OT) { float hh = fmaf(-A1c, h1, -A2c * h2); \
    OT = clip1f((ZB) + hh); h2 = h1; h1 = hh; }
#pragma unroll
    for (int q = 0; q < 8; ++q) {
      float4 o;
      CS(a[q].x, o.x) CS(a[q].y, o.y) CS(a[q].z, o.z) CS(a[q].w, o.w)
      ws4[WOFF + swzf(lane * 8 + q)] = o;
    }
#undef CS
  }

  // ---- coalesced store of own chunks (f >= 16) ----
  float* orow = out + (size_t)row * T_LEN;
#pragma unroll
  for (int q = 0; q < 8; ++q) {
    int f = q * 64 + lane;
    long g4 = base4 + f;
    if (f >= 16 && g4 < ROW4)
      reinterpret_cast<float4*>(orow)[g4] = ws4[WOFF + swzf(f)];
  }
}

// ---------------------------------------------------------------------------
extern "C" void kernel_launch(void* const* d_in, const int* in_sizes, int n_in,
                              void* d_out, int out_size, void* d_ws, size_t ws_size,
                              hipStream_t stream) {
  const float* x  = (const float*)d_in[0];   // (64, 160000)
  const float* nn = (const float*)d_in[1];   // (64, 160000)
  const float* cx = (const float*)d_in[2];   // (4,) a1,a2,b1,b2
  const float* cn = (const float*)d_in[3];   // (4,)
  float* out = (float*)d_out;                // (128, 160000) flat

  // ws layout: pay double[NBLK*6] | st u32[NBLK] | ticket u32  (~140 KB)
  double*   pay    = (double*)d_ws;
  unsigned* st     = (unsigned*)((char*)d_ws + (size_t)NBLK * 6 * 8);
  unsigned* ticket = st + NBLK;

  init_kernel<<<(NSTATE + 255) / 256, 256, 0, stream>>>(st);
  fused_kernel<<<NBLK, 256, 0, stream>>>(x, nn, cx, cn, pay, st, ticket, out);
}

// Round 20
// 60.457 us; speedup vs baseline: 3.1814x; 3.1814x over previous
//
#include <hip/hip_runtime.h>
#include <math.h>

// Problem geometry
#define T_LEN   160000
#define NROW    128        // 64 rows of x then 64 rows of n
#define CH      32         // samples per chunk
#define NCH     5000       // CH*NCH == T_LEN
#define OWNT    20         // chunks per thread in scan_row (256*20 >= 5000)
#define OWN_W   62         // own chunks per wave in emit (+2 warm = 64)
#define B_OWN   (4 * OWN_W)      // 248 own chunks per block
#define TILES   21               // ceil(5000/248)
#define NBLK    (NROW * TILES)   // 2688
#define ROW4    40000            // float4 per row

// HP biquad: y = x - 2 x1 + x2 + 1.99599 y1 - 0.996 y2
#define C1_HP ( 1.99599)
#define C2_HP (-0.996)
#define C1F   ( 1.99599f)
#define C2F   (-0.996f)

#define S1_FLOAT2S (NROW * NCH)          // 640000 float2 = 5,120,000 B
#define M2_BYTE_OFF (S1_FLOAT2S * 8)     // 16B-aligned

#define GLOBAL_AS __attribute__((address_space(1)))
#define SHARED_AS __attribute__((address_space(3)))

// clang-native vector types for nontemporal builtins (HIP float2/float4 are
// classes, rejected by __builtin_nontemporal_store)
typedef float nt2 __attribute__((ext_vector_type(2)));
typedef float nt4 __attribute__((ext_vector_type(4)));

// involutive swizzle (bits 3,4,5 XOR into 0,1,2) — async-load compatible
__device__ __forceinline__ int swzf(int F) { return F ^ ((F >> 3) & 7); }
__device__ __forceinline__ float clip1f(float v) { return fminf(fmaxf(v, -1.0f), 1.0f); }

// ---------------------------------------------------------------------------
// pass_a1: per (row, chunk) LOCAL stage-1 end state (zero y-init, true
// x-history). FIR f32, y-recurrence f64; e1 stored f32 (non-temporal).
// Block 0, threads 0/1 additionally emit M2 = A2stage^CH per filter.
// ---------------------------------------------------------------------------
__global__ __launch_bounds__(256) void pass_a1(const float* __restrict__ x,
                                               const float* __restrict__ nn,
                                               float2* __restrict__ e1,
                                               const float* __restrict__ cx,
                                               const float* __restrict__ cn,
                                               float4* __restrict__ m2) {
  int g = blockIdx.x * blockDim.x + threadIdx.x;
  if (g < 2) {                       // folded prep
    const float* c = g ? cn : cx;
    const float A1c = c[0], A2c = c[1];
    float pm2 = 0.f, pm1 = 0.f, p0 = 1.f;
#pragma unroll
    for (int k = 0; k < CH; ++k) {
      float pn = -A1c * p0 - A2c * pm1;
      pm2 = pm1; pm1 = p0; p0 = pn;
    }
    m2[g] = make_float4(p0, -A2c * pm1, pm1, -A2c * pm2);
  }
  if (g >= NROW * NCH) return;
  int row = g / NCH, c = g % NCH;
  const float* src = (row < 64) ? (x + (size_t)row * T_LEN)
                                : (nn + (size_t)(row - 64) * T_LEN);
  const float* xp = src + c * CH;
  float x1 = 0.f, x2 = 0.f;
  if (c) { x1 = xp[-1]; x2 = xp[-2]; }
  double y1 = 0.0, y2 = 0.0;
#pragma unroll
  for (int j = 0; j < CH; j += 4) {
    float4 xv = *reinterpret_cast<const float4*>(xp + j);
#define A1STEP(XF) { float xt = (XF); \
    float fir = (xt - 2.f * x1 + x2); \
    double y = fma(C1_HP, y1, fma(C2_HP, y2, (double)fir)); \
    x2 = x1; x1 = xt; y2 = y1; y1 = y; }
    A1STEP(xv.x) A1STEP(xv.y) A1STEP(xv.z) A1STEP(xv.w)
#undef A1STEP
  }
  nt2 ev; ev.x = (float)y1; ev.y = (float)y2;
  __builtin_nontemporal_store(ev, reinterpret_cast<nt2*>(&e1[g]));
}

// ---------------------------------------------------------------------------
// scan_row: one block (4 waves) per row; affine Kogge-Stone over chunk maps
// (f64 internal, f32 e-inputs); emits exact chunk-start states (f32).
// ---------------------------------------------------------------------------
__global__ __launch_bounds__(256) void scan_row(const float2* __restrict__ e,
                                                float2* __restrict__ s) {
  __shared__ double wm[4][6];
  const int t = threadIdx.x, row = blockIdx.x;
  const int lane = t & 63, wv = t >> 6;
  double pm2 = 0.0, pm1 = 0.0, p0 = 1.0;
#pragma unroll
  for (int k = 1; k <= CH; ++k) {
    double pn = C1_HP * p0 + C2_HP * pm1;
    pm2 = pm1; pm1 = p0; p0 = pn;
  }
  const double m00 = p0,  m01 = C2_HP * pm1;
  const double m10 = pm1, m11 = C2_HP * pm2;
  const float2* ep = e + (size_t)row * NCH;
  const int base = t * OWNT;
  double f1 = 0.0, f2 = 0.0;
  for (int j = 0; j < OWNT; ++j) {
    int c = base + j;
    float2 ev = (c < NCH) ? ep[c] : make_float2(0.f, 0.f);
    double n1 = m00 * f1 + m01 * f2 + (double)ev.x;
    double n2 = m10 * f1 + m11 * f2 + (double)ev.y;
    f1 = n1; f2 = n2;
  }
  double b00 = m00, b01 = m01, b10 = m10, b11 = m11;
  double r00 = 1.0, r01 = 0.0, r10 = 0.0, r11 = 1.0;
  int ee = OWNT;
  while (ee) {
    if (ee & 1) {
      double t00 = b00 * r00 + b01 * r10, t01 = b00 * r01 + b01 * r11;
      double t10 = b10 * r00 + b11 * r10, t11 = b10 * r01 + b11 * r11;
      r00 = t00; r01 = t01; r10 = t10; r11 = t11;
    }
    double q00 = b00 * b00 + b01 * b10, q01 = b00 * b01 + b01 * b11;
    double q10 = b10 * b00 + b11 * b10, q11 = b10 * b01 + b11 * b11;
    b00 = q00; b01 = q01; b10 = q10; b11 = q11;
    ee >>= 1;
  }
  double P00 = r00, P01 = r01, P10 = r10, P11 = r11, V1 = f1, V2 = f2;
#pragma unroll
  for (int off = 1; off < 64; off <<= 1) {
    double u00 = __shfl_up(P00, off), u01 = __shfl_up(P01, off);
    double u10 = __shfl_up(P10, off), u11 = __shfl_up(P11, off);
    double uv1 = __shfl_up(V1, off),  uv2 = __shfl_up(V2, off);
    if (lane >= off) {
      double nv1 = P00 * uv1 + P01 * uv2 + V1;
      double nv2 = P10 * uv1 + P11 * uv2 + V2;
      double n00 = P00 * u00 + P01 * u10, n01 = P00 * u01 + P01 * u11;
      double n10 = P10 * u00 + P11 * u10, n11 = P10 * u01 + P11 * u11;
      P00 = n00; P01 = n01; P10 = n10; P11 = n11; V1 = nv1; V2 = nv2;
    }
  }
  if (lane == 63) {
    wm[wv][0] = P00; wm[wv][1] = P01; wm[wv][2] = P10; wm[wv][3] = P11;
    wm[wv][4] = V1;  wm[wv][5] = V2;
  }
  __syncthreads();
  double S1 = 0.0, S2 = 0.0;
  for (int w = 0; w < wv; ++w) {
    double n1 = wm[w][0] * S1 + wm[w][1] * S2 + wm[w][4];
    double n2 = wm[w][2] * S1 + wm[w][3] * S2 + wm[w][5];
    S1 = n1; S2 = n2;
  }
  double q00 = __shfl_up(P00, 1), q01 = __shfl_up(P01, 1);
  double q10 = __shfl_up(P10, 1), q11 = __shfl_up(P11, 1);
  double qv1 = __shfl_up(V1, 1),  qv2 = __shfl_up(V2, 1);
  double st1, st2;
  if (lane == 0) { st1 = S1; st2 = S2; }
  else { st1 = q00 * S1 + q01 * S2 + qv1; st2 = q10 * S1 + q11 * S2 + qv2; }
  float2* sp = s + (size_t)row * NCH;
  double s1v = st1, s2v = st2;
  for (int j = 0; j < OWNT; ++j) {
    int c = base + j;
    if (c < NCH) {
      sp[c] = make_float2((float)s1v, (float)s2v);
      float2 ev = ep[c];
      double n1 = m00 * s1v + m01 * s2v + (double)ev.x;
      double n2 = m10 * s1v + m11 * s2v + (double)ev.y;
      s1v = n1; s2v = n2;
    }
  }
}

// ---------------------------------------------------------------------------
// emit (round-14 champion + NT stores): per-WAVE tiles (2 warm + 62 own
// chunks); lane owns one chunk. ZERO barriers. Interior tiles stage x via
// async global_load_lds (linear LDS dest, involutive swizzle folded into the
// global source index); boundary tiles manual. Then ds_read per chunk -> FIR
// -> fused stage1+stage2(zero-z) -> shfl e2 -> s2 = e2[c-1]+M2*e2[c-2] ->
// homogeneous correction + clip -> LDS write-back -> coalesced NT store.
// ---------------------------------------------------------------------------
__global__ __launch_bounds__(256, 5) void emit_kernel(const float* __restrict__ x,
                                                      const float* __restrict__ nn,
                                                      const float2* __restrict__ s1,
                                                      const float* __restrict__ cx,
                                                      const float* __restrict__ cn,
                                                      const float4* __restrict__ m2,
                                                      float* __restrict__ out) {
  __shared__ float4 ws4[2048];                 // 4 waves x 512 float4 = 32 KB
  const int tid = threadIdx.x, lane = tid & 63, wv = tid >> 6;
  const int b = blockIdx.x;
  const int row = b / TILES, tile = b % TILES;
  const int wave_c0 = tile * B_OWN + wv * OWN_W;   // first own chunk of wave
  const int cb = wave_c0 - 2 + lane;               // this lane's chunk
  const float* src = (row < 64) ? x + (size_t)row * T_LEN
                                : nn + (size_t)(row - 64) * T_LEN;
  const float4* src4 = reinterpret_cast<const float4*>(src);
  const float2* srow = s1 + (size_t)row * NCH;
  const float* cf = (row < 64) ? cx : cn;
  const float A1c = cf[0], A2c = cf[1], B1c = cf[2], B2c = cf[3];
  const float4 M2 = m2[(row < 64) ? 0 : 1];
  const bool valid = (cb >= 0) && (cb < NCH);

  // seed loads issued early (overlap with LDS staging)
  float sy1 = 0.f, sy2 = 0.f;
  if (valid && cb > 0) { float2 sv = srow[cb]; sy1 = sv.x; sy2 = sv.y; }
  float t0x = 0.f, t0y = 0.f;
  if (lane == 0 && valid && cb > 0) {
    float2 tp = *reinterpret_cast<const float2*>(src + (long)cb * CH - 2);
    t0y = tp.x; t0x = tp.y;           // x1 = tp.y, x2 = tp.x
  }

  const int WOFF = wv * 512;
  const long base4 = (long)(wave_c0 - 2) * 8;      // float4 units
  const bool interior = (base4 >= 0) && (base4 + 512 <= (long)ROW4);

  if (interior) {
    // async staging: LDS linear, involutive swizzle folded into global src
    const int lane_sz = lane ^ ((lane >> 3) & 7);
#pragma unroll
    for (int q = 0; q < 8; ++q) {
      const float4* gp = src4 + base4 + q * 64 + lane_sz;
      __builtin_amdgcn_global_load_lds(
          (const GLOBAL_AS void*)gp,
          (SHARED_AS void*)(ws4 + WOFF + q * 64),
          16, 0, 0);
    }
    asm volatile("s_waitcnt vmcnt(0)" ::: "memory");
  } else {
#pragma unroll
    for (int q = 0; q < 8; ++q) {
      int f = q * 64 + lane;
      long g4 = base4 + f;
      float4 v = make_float4(0.f, 0.f, 0.f, 0.f);
      if (g4 >= 0 && g4 < ROW4) v = src4[g4];
      ws4[WOFF + swzf(f)] = v;
    }
  }

  float4 a[8];
#pragma unroll
  for (int q = 0; q < 8; ++q) a[q] = ws4[WOFF + swzf(lane * 8 + q)];

  // x-tail of previous chunk from previous lane (lane 0: global)
  float tx = __shfl_up(a[7].w, 1);
  float ty = __shfl_up(a[7].z, 1);

  float x1, x2, y1, y2, v1, v2;
  if (valid && cb > 0) {
    y1 = sy1; y2 = sy2;
    v1 = clip1f(sy1); v2 = clip1f(sy2);
    if (lane == 0) { x1 = t0x; x2 = t0y; }
    else { x1 = tx; x2 = ty; }
  } else { x1 = 0.f; x2 = 0.f; y1 = 0.f; y2 = 0.f; v1 = 0.f; v2 = 0.f; }

  // ---- FIR precompute (input-only, parallel): a[q] := fir ----
  {
    float xp1 = x1, xp2 = x2;
#pragma unroll
    for (int q = 0; q < 8; ++q) {
      float4 t = a[q];
      float4 f;
      f.x = t.x - 2.f * xp1 + xp2;
      f.y = t.y - 2.f * t.x + xp1;
      f.z = t.z - 2.f * t.y + t.x;
      f.w = t.w - 2.f * t.z + t.y;
      xp2 = t.z; xp1 = t.w;
      a[q] = f;
    }
  }

  // ---- fused stage1 + stage2(zero-z), 1-fma/sample chains: a[q] := zb ----
  float z1 = 0.f, z2 = 0.f;
  if (valid) {
#define AB(REF) { \
    float yy = fmaf(C1F, y1, fmaf(C2F, y2, (REF))); \
    float vv = clip1f(yy); \
    float zz = fmaf(-A1c, z1, fmaf(-A2c, z2, fmaf(B2c, v2, fmaf(B1c, v1, vv)))); \
    y2 = y1; y1 = yy; v2 = v1; v1 = vv; z2 = z1; z1 = zz; REF = zz; }
#pragma unroll
    for (int q = 0; q < 8; ++q) { AB(a[q].x) AB(a[q].y) AB(a[q].z) AB(a[q].w) }
#undef AB
  }

  // e2 states of the two previous chunks via shuffles
  float u1x = __shfl_up(z1, 1), u1y = __shfl_up(z2, 1);
  float u2x = __shfl_up(z1, 2), u2y = __shfl_up(z2, 2);

  // ---- correction + clip, write back to LDS (own lanes only) ----
  if (lane >= 2 && valid) {
    float s2x, s2y;
    if (cb == 0)      { s2x = 0.f; s2y = 0.f; }
    else if (cb == 1) { s2x = u1x; s2y = u1y; }
    else {
      s2x = fmaf(M2.x, u2x, fmaf(M2.y, u2y, u1x));
      s2y = fmaf(M2.z, u2x, fmaf(M2.w, u2y, u1y));
    }
    float h1 = s2x, h2 = s2y;
#define CS(ZB, OT) { float hh = fmaf(-A1c, h1, -A2c * h2); \
    OT = clip1f((ZB) + hh); h2 = h1; h1 = hh; }
#pragma unroll
    for (int q = 0; q < 8; ++q) {
      float4 o;
      CS(a[q].x, o.x) CS(a[q].y, o.y) CS(a[q].z, o.z) CS(a[q].w, o.w)
      ws4[WOFF + swzf(lane * 8 + q)] = o;
    }
#undef CS
  }

  // ---- coalesced NON-TEMPORAL store of own chunks (f >= 16) ----
  nt4* orow4 = reinterpret_cast<nt4*>(out + (size_t)row * T_LEN);
#pragma unroll
  for (int q = 0; q < 8; ++q) {
    int f = q * 64 + lane;
    long g4 = base4 + f;
    if (f >= 16 && g4 < ROW4) {
      float4 v = ws4[WOFF + swzf(f)];
      nt4 nv; nv.x = v.x; nv.y = v.y; nv.z = v.z; nv.w = v.w;
      __builtin_nontemporal_store(nv, &orow4[g4]);
    }
  }
}

// ---------------------------------------------------------------------------
extern "C" void kernel_launch(void* const* d_in, const int* in_sizes, int n_in,
                              void* d_out, int out_size, void* d_ws, size_t ws_size,
                              hipStream_t stream) {
  const float* x  = (const float*)d_in[0];   // (64, 160000)
  const float* nn = (const float*)d_in[1];   // (64, 160000)
  const float* cx = (const float*)d_in[2];   // (4,) a1,a2,b1,b2
  const float* cn = (const float*)d_in[3];   // (4,)
  float* out = (float*)d_out;                // (128, 160000) flat

  // e1 (f32, 5.12 MB) aliases d_out: written by pass_a1, consumed by
  // scan_row, then fully overwritten by emit. s1 + m2 in ws.
  float2* e1 = (float2*)d_out;
  float2* s1 = (float2*)d_ws;
  float4* m2 = (float4*)((char*)d_ws + M2_BYTE_OFF);

  const int total = NROW * NCH;              // 640000
  const int blk = 256;
  const int nb = (total + blk - 1) / blk;    // 2500

  pass_a1<<<nb, blk, 0, stream>>>(x, nn, e1, cx, cn, m2);
  scan_row<<<NROW, blk, 0, stream>>>(e1, s1);
  emit_kernel<<<NBLK, blk, 0, stream>>>(x, nn, s1, cx, cn, m2, out);
}